// Round 24
// baseline (317.430 us; speedup 1.0000x reference)
//
#include <hip/hip_runtime.h>

// LoRA MLP: out = silu_mul(x@(Wgu + Agu@Bgu)) @ (Wd + Ad@Bd)
// T=16384, D_MODEL=1024, D_FF=2816 (2*D_FF=5632), RANK=16
//
// FINAL CHAMPION (R21 form; measured 317.97 / 316.56us across contexts;
// session best of 23 rounds; R1 baseline 456us -> -31%).
//  - Fused prologue (1 dispatch): W_eff = W + A@B transposed bf16 (LoRA
//    folded -> pure NT-GEMMs) + x -> bf16.
//  - gemm1 (194-196us, reproduced 8x): 256x128-dual tile, 8 waves, dual
//    gate/up accumulators + fused silu*mul epilogue.
//  - gemm2 (116.5us stable 1-step form): 256x256 tile, same pipeline.
//  - Pipeline: 4-buf global_load_lds DMA, counted vmcnt(4) (never 0 in
//    steady state), raw s_barrier, SGB {2 DS_READ : 5-6 MFMA} interleave
//    (+12%; R9 ablation: read/MFMA bursts otherwise serialize per wave),
//    granule-XOR LDS swizzle both sides, XCD-aware block swizzle.
// Ledger (race-free): top of iter kt: VMW(4) retires stage(kt+1)
// [outstanding {kt+1,kt+2}=8]; BARM publishes all waves' DMA; STAGE(kt+3);
// READ(buf (kt+1)&3); MFMA(kt). WAR: stage target last read 2 barriers ago.
// Tail: VMW(0) peel. (vmcnt is per-wave: read-after-stage must always be
// fenced by {per-wave wait -> barrier} - R6's lesson.)
//
// Workspace layout (bytes):
//   [0,            11534336)  Wgu_t  bf16 [5632][1024]
//   [11534336,     17301504)  Wd_t   bf16 [1024][2816]
//   [17301504,     50855936)  x_bf16      [16384][1024]
//   [50855936,    143130624)  h_bf16      [16384][2816]

typedef __bf16 bf16_t;
typedef __bf16 bf16x4 __attribute__((ext_vector_type(4)));
typedef __bf16 bf16x8 __attribute__((ext_vector_type(8)));
typedef float f32x4 __attribute__((ext_vector_type(4)));

#define TOKENS 16384
#define DMODEL 1024
#define DFF    2816
#define N2F    5632

#define BARM() asm volatile("s_barrier" ::: "memory")
#define VMW(n) asm volatile("s_waitcnt vmcnt(" #n ")" ::: "memory")
#define MFMA(d, va, vb) d = __builtin_amdgcn_mfma_f32_16x16x32_bf16(va, vb, d, 0, 0, 0)
#define LD8(p) (*(const bf16x8*)(p))
#define SGB(m, n) __builtin_amdgcn_sched_group_barrier(m, n, 0)
// per body: 4 VMEM(DMA), 12 DS_READ, 32 MFMA
#define SGB_PATTERN() do {                                                        \
    SGB(0x010, 4);                                                                \
    SGB(0x100, 2); SGB(0x008, 5);                                                 \
    SGB(0x100, 2); SGB(0x008, 5);                                                 \
    SGB(0x100, 2); SGB(0x008, 5);                                                 \
    SGB(0x100, 2); SGB(0x008, 5);                                                 \
    SGB(0x100, 2); SGB(0x008, 6);                                                 \
    SGB(0x100, 2); SGB(0x008, 6); } while (0)

__device__ __forceinline__ void gload16(const bf16_t* g, bf16_t* l) {
    __builtin_amdgcn_global_load_lds(
        (const __attribute__((address_space(1))) void*)g,
        (__attribute__((address_space(3))) void*)l, 16, 0, 0);
}

// ---------------------------------------------------------------------------
// prep body: W_eff_t[n][k] = bf16( W[k][n] + sum_r A[k][r]*B[r][n] )
template<int KTOT, int NTOT>
__device__ __forceinline__ void prep_body(
        const float* __restrict__ W, const float* __restrict__ A,
        const float* __restrict__ B, bf16_t* __restrict__ Wt,
        int k0, int n0, int t) {
    __shared__ float Ws[64][65];
    __shared__ float As[64][17];
    __shared__ float Bs[16][64];
    #pragma unroll
    for (int i = 0; i < 16; ++i) {
        int row = i * 4 + t / 64, col = t % 64;
        Ws[row][col] = W[(size_t)(k0 + row) * NTOT + n0 + col];
    }
    #pragma unroll
    for (int i = 0; i < 4; ++i) {
        int idx = i * 256 + t;
        As[idx / 16][idx % 16] = A[(size_t)(k0 + idx / 16) * 16 + idx % 16];
    }
    #pragma unroll
    for (int i = 0; i < 4; ++i) {
        int idx = i * 256 + t;
        Bs[idx / 64][idx % 64] = B[(size_t)(idx / 64) * NTOT + n0 + idx % 64];
    }
    __syncthreads();
    const int kl = t % 64;
    #pragma unroll
    for (int j = 0; j < 16; ++j) {
        int nl = j * 4 + t / 64;
        float val = Ws[kl][nl];
        #pragma unroll
        for (int r = 0; r < 16; ++r) val += As[kl][r] * Bs[r][nl];
        Wt[(size_t)(n0 + nl) * KTOT + k0 + kl] = (bf16_t)val;
    }
}

// Fused prologue: blocks [0,1408) prep Wgu_t; [1408,2112) prep Wd_t;
// [2112,18496) conv x -> bf16. All independent; branch is block-uniform.
__global__ __launch_bounds__(256) void prologue(
        const float* __restrict__ x,
        const float* __restrict__ Wgu, const float* __restrict__ Agu,
        const float* __restrict__ Bgu,
        const float* __restrict__ Wd,  const float* __restrict__ Ad,
        const float* __restrict__ Bd,
        bf16_t* __restrict__ wgut, bf16_t* __restrict__ wdt,
        bf16_t* __restrict__ xb) {
    const int b = blockIdx.x, t = threadIdx.x;
    if (b < 1408) {
        prep_body<DMODEL, N2F>(Wgu, Agu, Bgu, wgut,
                               (b & 15) * 64, (b >> 4) * 64, t);
    } else if (b < 2112) {
        const int b2 = b - 1408;
        prep_body<DFF, DMODEL>(Wd, Ad, Bd, wdt,
                               (b2 % 44) * 64, (b2 / 44) * 64, t);
    } else {
        const int i = (b - 2112) * 256 + t;
        float4 v = ((const float4*)x)[i];
        bf16x4 o;
        o.x = (bf16_t)v.x; o.y = (bf16_t)v.y; o.z = (bf16_t)v.z; o.w = (bf16_t)v.w;
        ((bf16x4*)xb)[i] = o;
    }
}

// ---------------------------------------------------------------------------
// GEMM1: h[T][DFF] = silu(g)*u, [g|u] = X[T][1024] @ Wgu_t^T
// Block 256(M) x 128(F)-dual; 8 waves 2M x 4F; wave = 128 rows x 32 f x {g,u}.
// Buf (16384 bf16 = 32KB): A[256][32] @0, Bg[128][32] @8192, Bu @12288.
// 4 bufs = 128KB.
__global__ __launch_bounds__(512, 2) void gemm1(
        const bf16_t* __restrict__ X, const bf16_t* __restrict__ Wt,
        bf16_t* __restrict__ H) {
    __shared__ bf16_t lds[65536];
    const int t = threadIdx.x, l = t & 63;
    const int wid = t >> 6, wr = wid >> 2, wc = wid & 3;
    const int l15 = l & 15, lhi = l >> 4;
    const int wgl = ((int)blockIdx.x & 7) * 176 + ((int)blockIdx.x >> 3);
    const int tf = wgl % 22, tm = wgl / 22;
    const int mbase = tm * 256, fbase = tf * 128;
    const int srow = t >> 2;
    const int sc8 = ((t & 3) ^ (srow & 3)) * 8;
    const bf16_t* gA  = X + (size_t)(mbase + srow) * DMODEL + sc8;
    const bf16_t* gA2 = gA + (size_t)128 * DMODEL;
    const bf16_t* gBg = Wt + (size_t)(fbase + srow) * DMODEL + sc8;
    const bf16_t* gBu = Wt + (size_t)(DFF + fbase + srow) * DMODEL + sc8;
    const int rsw = (lhi ^ (l15 & 3)) * 8;
    const int aoff = (wr * 128 + l15) * 32 + rsw;
    const int boff = 8192 + (wc * 32 + l15) * 32 + rsw;

    f32x4 accg[8][2] = {}, accu[8][2] = {};
    bf16x8 a0[8], g0[2], u0[2], a1[8], g1[2], u1[2];
    const int NT1 = DMODEL / 32;  // 32

#define G1_STAGE(kt) do { const int kc = (kt) * 32;                               \
    bf16_t* p = lds + (((kt) & 3) << 14) + wid * 512;                             \
    gload16(gA  + kc, p);                                                         \
    gload16(gA2 + kc, p + 4096);                                                  \
    gload16(gBg + kc, p + 8192);                                                  \
    gload16(gBu + kc, p + 12288); } while (0)
#define G1_READ(aa, gg, uu, bi) do {                                              \
    const bf16_t* _pa = lds + ((bi) << 14) + aoff;                                \
    aa[0] = LD8(_pa);        aa[1] = LD8(_pa + 512);                              \
    aa[2] = LD8(_pa + 1024); aa[3] = LD8(_pa + 1536);                             \
    aa[4] = LD8(_pa + 2048); aa[5] = LD8(_pa + 2560);                             \
    aa[6] = LD8(_pa + 3072); aa[7] = LD8(_pa + 3584);                             \
    const bf16_t* _pb = lds + ((bi) << 14) + boff;                                \
    gg[0] = LD8(_pb);        gg[1] = LD8(_pb + 512);                              \
    uu[0] = LD8(_pb + 4096); uu[1] = LD8(_pb + 4608); } while (0)
#define G1_MFMA(aa, gg, uu) do {                                                  \
    _Pragma("unroll")                                                             \
    for (int m = 0; m < 8; ++m) {                                                 \
        MFMA(accg[m][0], aa[m], gg[0]); MFMA(accu[m][0], aa[m], uu[0]);           \
        MFMA(accg[m][1], aa[m], gg[1]); MFMA(accu[m][1], aa[m], uu[1]);           \
    } } while (0)
#define G1_ITER(kt, aaU, ggU, uuU, aaR, ggR, uuR) do {                            \
    VMW(4); BARM();                                                               \
    if ((kt) + 3 < NT1) G1_STAGE((kt) + 3);                                       \
    G1_READ(aaR, ggR, uuR, ((kt) + 1) & 3);                                       \
    G1_MFMA(aaU, ggU, uuU);                                                       \
    SGB_PATTERN(); } while (0)

    G1_STAGE(0); G1_STAGE(1); G1_STAGE(2);
    VMW(8); BARM();
    G1_READ(a0, g0, u0, 0);
    for (int kt2 = 0; kt2 < NT1 - 2; kt2 += 2) {
        G1_ITER(kt2,     a0, g0, u0, a1, g1, u1);
        G1_ITER(kt2 + 1, a1, g1, u1, a0, g0, u0);
    }
    VMW(0); BARM();
    G1_READ(a1, g1, u1, (NT1 - 1) & 3);
    G1_MFMA(a0, g0, u0);
    G1_MFMA(a1, g1, u1);
#undef G1_ITER
#undef G1_STAGE
#undef G1_READ
#undef G1_MFMA

    #pragma unroll
    for (int m = 0; m < 8; ++m)
        #pragma unroll
        for (int n = 0; n < 2; ++n)
            #pragma unroll
            for (int r = 0; r < 4; ++r) {
                int row = mbase + wr * 128 + m * 16 + lhi * 4 + r;
                int col = fbase + wc * 32 + n * 16 + l15;
                float g = accg[m][n][r], u = accu[m][n][r];
                H[(size_t)row * DFF + col] = (bf16_t)(g / (1.0f + __expf(-g)) * u);
            }
}

// ---------------------------------------------------------------------------
// GEMM2: out[T][1024] = H[T][2816] @ Wd_t^T   (fp32 out)
// Block 256(M) x 256(N); 8 waves 2M x 4N; wave 128x64. Same pipeline.
// Buf (16384 bf16): A[256][32] @0, B[256][32] @8192. 4 bufs = 128KB.
__global__ __launch_bounds__(512, 2) void gemm2(
        const bf16_t* __restrict__ Hm, const bf16_t* __restrict__ Wt,
        float* __restrict__ O) {
    __shared__ bf16_t lds[65536];
    const int t = threadIdx.x, l = t & 63;
    const int wid = t >> 6, wr = wid >> 2, wc = wid & 3;
    const int l15 = l & 15, lhi = l >> 4;
    const int wgl = ((int)blockIdx.x & 7) * 32 + ((int)blockIdx.x >> 3);
    const int tn = wgl % 4, tm = wgl / 4;
    const int mbase = tm * 256, nbase = tn * 256;
    const int srow = t >> 2;
    const int sc8 = ((t & 3) ^ (srow & 3)) * 8;
    const bf16_t* gA  = Hm + (size_t)(mbase + srow) * DFF + sc8;
    const bf16_t* gA2 = gA + (size_t)128 * DFF;
    const bf16_t* gB  = Wt + (size_t)(nbase + srow) * DFF + sc8;
    const bf16_t* gB2 = gB + (size_t)128 * DFF;
    const int rsw = (lhi ^ (l15 & 3)) * 8;
    const int aoff = (wr * 128 + l15) * 32 + rsw;
    const int boff = 8192 + (wc * 64 + l15) * 32 + rsw;

    f32x4 acc[8][4] = {};
    bf16x8 a0[8], b0[4], a1[8], b1[4];
    const int NT2 = DFF / 32;  // 88

#define G2_STAGE(kt) do { const int kc = (kt) * 32;                               \
    bf16_t* p = lds + (((kt) & 3) << 14) + wid * 512;                             \
    gload16(gA  + kc, p);                                                         \
    gload16(gA2 + kc, p + 4096);                                                  \
    gload16(gB  + kc, p + 8192);                                                  \
    gload16(gB2 + kc, p + 12288); } while (0)
#define G2_READ(aa, bb, bi) do {                                                  \
    const bf16_t* _pa = lds + ((bi) << 14) + aoff;                                \
    aa[0] = LD8(_pa);        aa[1] = LD8(_pa + 512);                              \
    aa[2] = LD8(_pa + 1024); aa[3] = LD8(_pa + 1536);                             \
    aa[4] = LD8(_pa + 2048); aa[5] = LD8(_pa + 2560);                             \
    aa[6] = LD8(_pa + 3072); aa[7] = LD8(_pa + 3584);                             \
    const bf16_t* _pb = lds + ((bi) << 14) + boff;                                \
    bb[0] = LD8(_pb);        bb[1] = LD8(_pb + 512);                              \
    bb[2] = LD8(_pb + 1024); bb[3] = LD8(_pb + 1536); } while (0)
#define G2_MFMA(aa, bb) do {                                                      \
    _Pragma("unroll")                                                             \
    for (int m = 0; m < 8; ++m) {                                                 \
        MFMA(acc[m][0], aa[m], bb[0]); MFMA(acc[m][1], aa[m], bb[1]);             \
        MFMA(acc[m][2], aa[m], bb[2]); MFMA(acc[m][3], aa[m], bb[3]);             \
    } } while (0)
#define G2_ITER(kt, aaU, bbU, aaR, bbR) do {                                      \
    VMW(4); BARM();                                                               \
    if ((kt) + 3 < NT2) G2_STAGE((kt) + 3);                                       \
    G2_READ(aaR, bbR, ((kt) + 1) & 3);                                            \
    G2_MFMA(aaU, bbU);                                                            \
    SGB_PATTERN(); } while (0)

    G2_STAGE(0); G2_STAGE(1); G2_STAGE(2);
    VMW(8); BARM();
    G2_READ(a0, b0, 0);
    for (int kt2 = 0; kt2 < NT2 - 2; kt2 += 2) {
        G2_ITER(kt2,     a0, b0, a1, b1);
        G2_ITER(kt2 + 1, a1, b1, a0, b0);
    }
    VMW(0); BARM();
    G2_READ(a1, b1, (NT2 - 1) & 3);
    G2_MFMA(a0, b0);
    G2_MFMA(a1, b1);
#undef G2_STAGE
#undef G2_READ
#undef G2_MFMA
#undef G2_ITER

    #pragma unroll
    for (int m = 0; m < 8; ++m)
        #pragma unroll
        for (int n = 0; n < 4; ++n)
            #pragma unroll
            for (int r = 0; r < 4; ++r) {
                int row = mbase + wr * 128 + m * 16 + lhi * 4 + r;
                int col = nbase + wc * 64 + n * 16 + l15;
                O[(size_t)row * DMODEL + col] = acc[m][n][r];
            }
}

// ---------------------------------------------------------------------------
extern "C" void kernel_launch(void* const* d_in, const int* in_sizes, int n_in,
                              void* d_out, int out_size, void* d_ws, size_t ws_size,
                              hipStream_t stream) {
    const float* x   = (const float*)d_in[0];
    const float* Wgu = (const float*)d_in[1];
    const float* Agu = (const float*)d_in[2];
    const float* Bgu = (const float*)d_in[3];
    const float* Wd  = (const float*)d_in[4];
    const float* Ad  = (const float*)d_in[5];
    const float* Bd  = (const float*)d_in[6];
    float* out = (float*)d_out;
    char* ws = (char*)d_ws;

    bf16_t* wgut = (bf16_t*)(ws);                    // [5632][1024]
    bf16_t* wdt  = (bf16_t*)(ws + 11534336);         // [1024][2816]
    bf16_t* xb   = (bf16_t*)(ws + 17301504);         // [16384][1024]
    bf16_t* hb   = (bf16_t*)(ws + 50855936);         // [16384][2816]

    prologue<<<18496, 256, 0, stream>>>(x, Wgu, Agu, Bgu, Wd, Ad, Bd,
                                        wgut, wdt, xb);
    gemm1<<<22 * 64, 512, 0, stream>>>(xb, wgut, hb);
    gemm2<<<8 * 32, 512, 0, stream>>>(hb, wdt, out);
}

// Round 25
// 315.087 us; speedup vs baseline: 1.0074x; 1.0074x over previous
//
#include <hip/hip_runtime.h>

// LoRA MLP: out = silu_mul(x@(Wgu + Agu@Bgu)) @ (Wd + Ad@Bd)
// T=16384, D_MODEL=1024, D_FF=2816 (2*D_FF=5632), RANK=16
//
// FINAL CHAMPION (measured 317.97 / 316.56 / 317.43us across contexts;
// session best of 24 rounds; R1 baseline 456us -> -31%).
//  - Fused prologue (1 dispatch): W_eff = W + A@B transposed bf16 (LoRA
//    folded -> pure NT-GEMMs) + x -> bf16.
//  - gemm1 (194-196us, reproduced 9x): 256x128-dual tile, 8 waves, dual
//    gate/up accumulators + fused silu*mul epilogue.
//  - gemm2 (116.5us stable 1-step form): 256x256 tile, same pipeline.
//  - Pipeline: 4-buf global_load_lds DMA, counted vmcnt(4) (never 0 in
//    steady state), raw s_barrier, SGB {2 DS_READ : 5-6 MFMA} interleave
//    (+12%; R9 ablation: read/MFMA bursts otherwise serialize per wave),
//    granule-XOR LDS swizzle both sides, XCD-aware block swizzle.
// Ledger (race-free): top of iter kt: VMW(4) retires stage(kt+1)
// [outstanding {kt+1,kt+2}=8]; BARM publishes all waves' DMA; STAGE(kt+3);
// READ(buf (kt+1)&3); MFMA(kt). WAR: stage target last read 2 barriers ago.
// Tail: VMW(0) peel. (vmcnt is per-wave: read-after-stage must always be
// fenced by {per-wave wait -> barrier} - R6's lesson.)
//
// Workspace layout (bytes):
//   [0,            11534336)  Wgu_t  bf16 [5632][1024]
//   [11534336,     17301504)  Wd_t   bf16 [1024][2816]
//   [17301504,     50855936)  x_bf16      [16384][1024]
//   [50855936,    143130624)  h_bf16      [16384][2816]

typedef __bf16 bf16_t;
typedef __bf16 bf16x4 __attribute__((ext_vector_type(4)));
typedef __bf16 bf16x8 __attribute__((ext_vector_type(8)));
typedef float f32x4 __attribute__((ext_vector_type(4)));

#define TOKENS 16384
#define DMODEL 1024
#define DFF    2816
#define N2F    5632

#define BARM() asm volatile("s_barrier" ::: "memory")
#define VMW(n) asm volatile("s_waitcnt vmcnt(" #n ")" ::: "memory")
#define MFMA(d, va, vb) d = __builtin_amdgcn_mfma_f32_16x16x32_bf16(va, vb, d, 0, 0, 0)
#define LD8(p) (*(const bf16x8*)(p))
#define SGB(m, n) __builtin_amdgcn_sched_group_barrier(m, n, 0)
// per body: 4 VMEM(DMA), 12 DS_READ, 32 MFMA
#define SGB_PATTERN() do {                                                        \
    SGB(0x010, 4);                                                                \
    SGB(0x100, 2); SGB(0x008, 5);                                                 \
    SGB(0x100, 2); SGB(0x008, 5);                                                 \
    SGB(0x100, 2); SGB(0x008, 5);                                                 \
    SGB(0x100, 2); SGB(0x008, 5);                                                 \
    SGB(0x100, 2); SGB(0x008, 6);                                                 \
    SGB(0x100, 2); SGB(0x008, 6); } while (0)

__device__ __forceinline__ void gload16(const bf16_t* g, bf16_t* l) {
    __builtin_amdgcn_global_load_lds(
        (const __attribute__((address_space(1))) void*)g,
        (__attribute__((address_space(3))) void*)l, 16, 0, 0);
}

// ---------------------------------------------------------------------------
// prep body: W_eff_t[n][k] = bf16( W[k][n] + sum_r A[k][r]*B[r][n] )
template<int KTOT, int NTOT>
__device__ __forceinline__ void prep_body(
        const float* __restrict__ W, const float* __restrict__ A,
        const float* __restrict__ B, bf16_t* __restrict__ Wt,
        int k0, int n0, int t) {
    __shared__ float Ws[64][65];
    __shared__ float As[64][17];
    __shared__ float Bs[16][64];
    #pragma unroll
    for (int i = 0; i < 16; ++i) {
        int row = i * 4 + t / 64, col = t % 64;
        Ws[row][col] = W[(size_t)(k0 + row) * NTOT + n0 + col];
    }
    #pragma unroll
    for (int i = 0; i < 4; ++i) {
        int idx = i * 256 + t;
        As[idx / 16][idx % 16] = A[(size_t)(k0 + idx / 16) * 16 + idx % 16];
    }
    #pragma unroll
    for (int i = 0; i < 4; ++i) {
        int idx = i * 256 + t;
        Bs[idx / 64][idx % 64] = B[(size_t)(idx / 64) * NTOT + n0 + idx % 64];
    }
    __syncthreads();
    const int kl = t % 64;
    #pragma unroll
    for (int j = 0; j < 16; ++j) {
        int nl = j * 4 + t / 64;
        float val = Ws[kl][nl];
        #pragma unroll
        for (int r = 0; r < 16; ++r) val += As[kl][r] * Bs[r][nl];
        Wt[(size_t)(n0 + nl) * KTOT + k0 + kl] = (bf16_t)val;
    }
}

// Fused prologue: blocks [0,1408) prep Wgu_t; [1408,2112) prep Wd_t;
// [2112,18496) conv x -> bf16. All independent; branch is block-uniform.
__global__ __launch_bounds__(256) void prologue(
        const float* __restrict__ x,
        const float* __restrict__ Wgu, const float* __restrict__ Agu,
        const float* __restrict__ Bgu,
        const float* __restrict__ Wd,  const float* __restrict__ Ad,
        const float* __restrict__ Bd,
        bf16_t* __restrict__ wgut, bf16_t* __restrict__ wdt,
        bf16_t* __restrict__ xb) {
    const int b = blockIdx.x, t = threadIdx.x;
    if (b < 1408) {
        prep_body<DMODEL, N2F>(Wgu, Agu, Bgu, wgut,
                               (b & 15) * 64, (b >> 4) * 64, t);
    } else if (b < 2112) {
        const int b2 = b - 1408;
        prep_body<DFF, DMODEL>(Wd, Ad, Bd, wdt,
                               (b2 % 44) * 64, (b2 / 44) * 64, t);
    } else {
        const int i = (b - 2112) * 256 + t;
        float4 v = ((const float4*)x)[i];
        bf16x4 o;
        o.x = (bf16_t)v.x; o.y = (bf16_t)v.y; o.z = (bf16_t)v.z; o.w = (bf16_t)v.w;
        ((bf16x4*)xb)[i] = o;
    }
}

// ---------------------------------------------------------------------------
// GEMM1: h[T][DFF] = silu(g)*u, [g|u] = X[T][1024] @ Wgu_t^T
// Block 256(M) x 128(F)-dual; 8 waves 2M x 4F; wave = 128 rows x 32 f x {g,u}.
// Buf (16384 bf16 = 32KB): A[256][32] @0, Bg[128][32] @8192, Bu @12288.
// 4 bufs = 128KB.
__global__ __launch_bounds__(512, 2) void gemm1(
        const bf16_t* __restrict__ X, const bf16_t* __restrict__ Wt,
        bf16_t* __restrict__ H) {
    __shared__ bf16_t lds[65536];
    const int t = threadIdx.x, l = t & 63;
    const int wid = t >> 6, wr = wid >> 2, wc = wid & 3;
    const int l15 = l & 15, lhi = l >> 4;
    const int wgl = ((int)blockIdx.x & 7) * 176 + ((int)blockIdx.x >> 3);
    const int tf = wgl % 22, tm = wgl / 22;
    const int mbase = tm * 256, fbase = tf * 128;
    const int srow = t >> 2;
    const int sc8 = ((t & 3) ^ (srow & 3)) * 8;
    const bf16_t* gA  = X + (size_t)(mbase + srow) * DMODEL + sc8;
    const bf16_t* gA2 = gA + (size_t)128 * DMODEL;
    const bf16_t* gBg = Wt + (size_t)(fbase + srow) * DMODEL + sc8;
    const bf16_t* gBu = Wt + (size_t)(DFF + fbase + srow) * DMODEL + sc8;
    const int rsw = (lhi ^ (l15 & 3)) * 8;
    const int aoff = (wr * 128 + l15) * 32 + rsw;
    const int boff = 8192 + (wc * 32 + l15) * 32 + rsw;

    f32x4 accg[8][2] = {}, accu[8][2] = {};
    bf16x8 a0[8], g0[2], u0[2], a1[8], g1[2], u1[2];
    const int NT1 = DMODEL / 32;  // 32

#define G1_STAGE(kt) do { const int kc = (kt) * 32;                               \
    bf16_t* p = lds + (((kt) & 3) << 14) + wid * 512;                             \
    gload16(gA  + kc, p);                                                         \
    gload16(gA2 + kc, p + 4096);                                                  \
    gload16(gBg + kc, p + 8192);                                                  \
    gload16(gBu + kc, p + 12288); } while (0)
#define G1_READ(aa, gg, uu, bi) do {                                              \
    const bf16_t* _pa = lds + ((bi) << 14) + aoff;                                \
    aa[0] = LD8(_pa);        aa[1] = LD8(_pa + 512);                              \
    aa[2] = LD8(_pa + 1024); aa[3] = LD8(_pa + 1536);                             \
    aa[4] = LD8(_pa + 2048); aa[5] = LD8(_pa + 2560);                             \
    aa[6] = LD8(_pa + 3072); aa[7] = LD8(_pa + 3584);                             \
    const bf16_t* _pb = lds + ((bi) << 14) + boff;                                \
    gg[0] = LD8(_pb);        gg[1] = LD8(_pb + 512);                              \
    uu[0] = LD8(_pb + 4096); uu[1] = LD8(_pb + 4608); } while (0)
#define G1_MFMA(aa, gg, uu) do {                                                  \
    _Pragma("unroll")                                                             \
    for (int m = 0; m < 8; ++m) {                                                 \
        MFMA(accg[m][0], aa[m], gg[0]); MFMA(accu[m][0], aa[m], uu[0]);           \
        MFMA(accg[m][1], aa[m], gg[1]); MFMA(accu[m][1], aa[m], uu[1]);           \
    } } while (0)
#define G1_ITER(kt, aaU, ggU, uuU, aaR, ggR, uuR) do {                            \
    VMW(4); BARM();                                                               \
    if ((kt) + 3 < NT1) G1_STAGE((kt) + 3);                                       \
    G1_READ(aaR, ggR, uuR, ((kt) + 1) & 3);                                       \
    G1_MFMA(aaU, ggU, uuU);                                                       \
    SGB_PATTERN(); } while (0)

    G1_STAGE(0); G1_STAGE(1); G1_STAGE(2);
    VMW(8); BARM();
    G1_READ(a0, g0, u0, 0);
    for (int kt2 = 0; kt2 < NT1 - 2; kt2 += 2) {
        G1_ITER(kt2,     a0, g0, u0, a1, g1, u1);
        G1_ITER(kt2 + 1, a1, g1, u1, a0, g0, u0);
    }
    VMW(0); BARM();
    G1_READ(a1, g1, u1, (NT1 - 1) & 3);
    G1_MFMA(a0, g0, u0);
    G1_MFMA(a1, g1, u1);
#undef G1_ITER
#undef G1_STAGE
#undef G1_READ
#undef G1_MFMA

    #pragma unroll
    for (int m = 0; m < 8; ++m)
        #pragma unroll
        for (int n = 0; n < 2; ++n)
            #pragma unroll
            for (int r = 0; r < 4; ++r) {
                int row = mbase + wr * 128 + m * 16 + lhi * 4 + r;
                int col = fbase + wc * 32 + n * 16 + l15;
                float g = accg[m][n][r], u = accu[m][n][r];
                H[(size_t)row * DFF + col] = (bf16_t)(g / (1.0f + __expf(-g)) * u);
            }
}

// ---------------------------------------------------------------------------
// GEMM2: out[T][1024] = H[T][2816] @ Wd_t^T   (fp32 out)
// Block 256(M) x 256(N); 8 waves 2M x 4N; wave 128x64. Same pipeline.
// Buf (16384 bf16): A[256][32] @0, B[256][32] @8192. 4 bufs = 128KB.
__global__ __launch_bounds__(512, 2) void gemm2(
        const bf16_t* __restrict__ Hm, const bf16_t* __restrict__ Wt,
        float* __restrict__ O) {
    __shared__ bf16_t lds[65536];
    const int t = threadIdx.x, l = t & 63;
    const int wid = t >> 6, wr = wid >> 2, wc = wid & 3;
    const int l15 = l & 15, lhi = l >> 4;
    const int wgl = ((int)blockIdx.x & 7) * 32 + ((int)blockIdx.x >> 3);
    const int tn = wgl % 4, tm = wgl / 4;
    const int mbase = tm * 256, nbase = tn * 256;
    const int srow = t >> 2;
    const int sc8 = ((t & 3) ^ (srow & 3)) * 8;
    const bf16_t* gA  = Hm + (size_t)(mbase + srow) * DFF + sc8;
    const bf16_t* gA2 = gA + (size_t)128 * DFF;
    const bf16_t* gB  = Wt + (size_t)(nbase + srow) * DFF + sc8;
    const bf16_t* gB2 = gB + (size_t)128 * DFF;
    const int rsw = (lhi ^ (l15 & 3)) * 8;
    const int aoff = (wr * 128 + l15) * 32 + rsw;
    const int boff = 8192 + (wc * 64 + l15) * 32 + rsw;

    f32x4 acc[8][4] = {};
    bf16x8 a0[8], b0[4], a1[8], b1[4];
    const int NT2 = DFF / 32;  // 88

#define G2_STAGE(kt) do { const int kc = (kt) * 32;                               \
    bf16_t* p = lds + (((kt) & 3) << 14) + wid * 512;                             \
    gload16(gA  + kc, p);                                                         \
    gload16(gA2 + kc, p + 4096);                                                  \
    gload16(gB  + kc, p + 8192);                                                  \
    gload16(gB2 + kc, p + 12288); } while (0)
#define G2_READ(aa, bb, bi) do {                                                  \
    const bf16_t* _pa = lds + ((bi) << 14) + aoff;                                \
    aa[0] = LD8(_pa);        aa[1] = LD8(_pa + 512);                              \
    aa[2] = LD8(_pa + 1024); aa[3] = LD8(_pa + 1536);                             \
    aa[4] = LD8(_pa + 2048); aa[5] = LD8(_pa + 2560);                             \
    aa[6] = LD8(_pa + 3072); aa[7] = LD8(_pa + 3584);                             \
    const bf16_t* _pb = lds + ((bi) << 14) + boff;                                \
    bb[0] = LD8(_pb);        bb[1] = LD8(_pb + 512);                              \
    bb[2] = LD8(_pb + 1024); bb[3] = LD8(_pb + 1536); } while (0)
#define G2_MFMA(aa, bb) do {                                                      \
    _Pragma("unroll")                                                             \
    for (int m = 0; m < 8; ++m) {                                                 \
        MFMA(acc[m][0], aa[m], bb[0]); MFMA(acc[m][1], aa[m], bb[1]);             \
        MFMA(acc[m][2], aa[m], bb[2]); MFMA(acc[m][3], aa[m], bb[3]);             \
    } } while (0)
#define G2_ITER(kt, aaU, bbU, aaR, bbR) do {                                      \
    VMW(4); BARM();                                                               \
    if ((kt) + 3 < NT2) G2_STAGE((kt) + 3);                                       \
    G2_READ(aaR, bbR, ((kt) + 1) & 3);                                            \
    G2_MFMA(aaU, bbU);                                                            \
    SGB_PATTERN(); } while (0)

    G2_STAGE(0); G2_STAGE(1); G2_STAGE(2);
    VMW(8); BARM();
    G2_READ(a0, b0, 0);
    for (int kt2 = 0; kt2 < NT2 - 2; kt2 += 2) {
        G2_ITER(kt2,     a0, b0, a1, b1);
        G2_ITER(kt2 + 1, a1, b1, a0, b0);
    }
    VMW(0); BARM();
    G2_READ(a1, b1, (NT2 - 1) & 3);
    G2_MFMA(a0, b0);
    G2_MFMA(a1, b1);
#undef G2_STAGE
#undef G2_READ
#undef G2_MFMA
#undef G2_ITER

    #pragma unroll
    for (int m = 0; m < 8; ++m)
        #pragma unroll
        for (int n = 0; n < 4; ++n)
            #pragma unroll
            for (int r = 0; r < 4; ++r) {
                int row = mbase + wr * 128 + m * 16 + lhi * 4 + r;
                int col = nbase + wc * 64 + n * 16 + l15;
                O[(size_t)row * DMODEL + col] = acc[m][n][r];
            }
}

// ---------------------------------------------------------------------------
extern "C" void kernel_launch(void* const* d_in, const int* in_sizes, int n_in,
                              void* d_out, int out_size, void* d_ws, size_t ws_size,
                              hipStream_t stream) {
    const float* x   = (const float*)d_in[0];
    const float* Wgu = (const float*)d_in[1];
    const float* Agu = (const float*)d_in[2];
    const float* Bgu = (const float*)d_in[3];
    const float* Wd  = (const float*)d_in[4];
    const float* Ad  = (const float*)d_in[5];
    const float* Bd  = (const float*)d_in[6];
    float* out = (float*)d_out;
    char* ws = (char*)d_ws;

    bf16_t* wgut = (bf16_t*)(ws);                    // [5632][1024]
    bf16_t* wdt  = (bf16_t*)(ws + 11534336);         // [1024][2816]
    bf16_t* xb   = (bf16_t*)(ws + 17301504);         // [16384][1024]
    bf16_t* hb   = (bf16_t*)(ws + 50855936);         // [16384][2816]

    prologue<<<18496, 256, 0, stream>>>(x, Wgu, Agu, Bgu, Wd, Ad, Bd,
                                        wgut, wdt, xb);
    gemm1<<<22 * 64, 512, 0, stream>>>(xb, wgut, hb);
    gemm2<<<8 * 32, 512, 0, stream>>>(hb, wdt, out);
}

// Round 26
// 315.005 us; speedup vs baseline: 1.0077x; 1.0003x over previous
//
#include <hip/hip_runtime.h>

// LoRA MLP: out = silu_mul(x@(Wgu + Agu@Bgu)) @ (Wd + Ad@Bd)
// T=16384, D_MODEL=1024, D_FF=2816 (2*D_FF=5632), RANK=16
//
// FINAL CHAMPION (measured 317.97 / 316.56 / 317.43 / 315.09us across
// contexts; session best of 25 rounds; R1 baseline 456us -> -31%).
//  - Fused prologue (1 dispatch): W_eff = W + A@B transposed bf16 (LoRA
//    folded -> pure NT-GEMMs) + x -> bf16.
//  - gemm1 (194-196us, reproduced 10x): 256x128-dual tile, 8 waves, dual
//    gate/up accumulators + fused silu*mul epilogue.
//  - gemm2 (116.5us stable 1-step form): 256x256 tile, same pipeline.
//  - Pipeline: 4-buf global_load_lds DMA, counted vmcnt(4) (never 0 in
//    steady state), raw s_barrier, SGB {2 DS_READ : 5-6 MFMA} interleave
//    (+12%; R9 ablation: read/MFMA bursts otherwise serialize per wave),
//    granule-XOR LDS swizzle both sides, XCD-aware block swizzle.
// Ledger (race-free): top of iter kt: VMW(4) retires stage(kt+1)
// [outstanding {kt+1,kt+2}=8]; BARM publishes all waves' DMA; STAGE(kt+3);
// READ(buf (kt+1)&3); MFMA(kt). WAR: stage target last read 2 barriers ago.
// Tail: VMW(0) peel. (vmcnt is per-wave: read-after-stage must always be
// fenced by {per-wave wait -> barrier} - R6's lesson.)
//
// Workspace layout (bytes):
//   [0,            11534336)  Wgu_t  bf16 [5632][1024]
//   [11534336,     17301504)  Wd_t   bf16 [1024][2816]
//   [17301504,     50855936)  x_bf16      [16384][1024]
//   [50855936,    143130624)  h_bf16      [16384][2816]

typedef __bf16 bf16_t;
typedef __bf16 bf16x4 __attribute__((ext_vector_type(4)));
typedef __bf16 bf16x8 __attribute__((ext_vector_type(8)));
typedef float f32x4 __attribute__((ext_vector_type(4)));

#define TOKENS 16384
#define DMODEL 1024
#define DFF    2816
#define N2F    5632

#define BARM() asm volatile("s_barrier" ::: "memory")
#define VMW(n) asm volatile("s_waitcnt vmcnt(" #n ")" ::: "memory")
#define MFMA(d, va, vb) d = __builtin_amdgcn_mfma_f32_16x16x32_bf16(va, vb, d, 0, 0, 0)
#define LD8(p) (*(const bf16x8*)(p))
#define SGB(m, n) __builtin_amdgcn_sched_group_barrier(m, n, 0)
// per body: 4 VMEM(DMA), 12 DS_READ, 32 MFMA
#define SGB_PATTERN() do {                                                        \
    SGB(0x010, 4);                                                                \
    SGB(0x100, 2); SGB(0x008, 5);                                                 \
    SGB(0x100, 2); SGB(0x008, 5);                                                 \
    SGB(0x100, 2); SGB(0x008, 5);                                                 \
    SGB(0x100, 2); SGB(0x008, 5);                                                 \
    SGB(0x100, 2); SGB(0x008, 6);                                                 \
    SGB(0x100, 2); SGB(0x008, 6); } while (0)

__device__ __forceinline__ void gload16(const bf16_t* g, bf16_t* l) {
    __builtin_amdgcn_global_load_lds(
        (const __attribute__((address_space(1))) void*)g,
        (__attribute__((address_space(3))) void*)l, 16, 0, 0);
}

// ---------------------------------------------------------------------------
// prep body: W_eff_t[n][k] = bf16( W[k][n] + sum_r A[k][r]*B[r][n] )
template<int KTOT, int NTOT>
__device__ __forceinline__ void prep_body(
        const float* __restrict__ W, const float* __restrict__ A,
        const float* __restrict__ B, bf16_t* __restrict__ Wt,
        int k0, int n0, int t) {
    __shared__ float Ws[64][65];
    __shared__ float As[64][17];
    __shared__ float Bs[16][64];
    #pragma unroll
    for (int i = 0; i < 16; ++i) {
        int row = i * 4 + t / 64, col = t % 64;
        Ws[row][col] = W[(size_t)(k0 + row) * NTOT + n0 + col];
    }
    #pragma unroll
    for (int i = 0; i < 4; ++i) {
        int idx = i * 256 + t;
        As[idx / 16][idx % 16] = A[(size_t)(k0 + idx / 16) * 16 + idx % 16];
    }
    #pragma unroll
    for (int i = 0; i < 4; ++i) {
        int idx = i * 256 + t;
        Bs[idx / 64][idx % 64] = B[(size_t)(idx / 64) * NTOT + n0 + idx % 64];
    }
    __syncthreads();
    const int kl = t % 64;
    #pragma unroll
    for (int j = 0; j < 16; ++j) {
        int nl = j * 4 + t / 64;
        float val = Ws[kl][nl];
        #pragma unroll
        for (int r = 0; r < 16; ++r) val += As[kl][r] * Bs[r][nl];
        Wt[(size_t)(n0 + nl) * KTOT + k0 + kl] = (bf16_t)val;
    }
}

// Fused prologue: blocks [0,1408) prep Wgu_t; [1408,2112) prep Wd_t;
// [2112,18496) conv x -> bf16. All independent; branch is block-uniform.
__global__ __launch_bounds__(256) void prologue(
        const float* __restrict__ x,
        const float* __restrict__ Wgu, const float* __restrict__ Agu,
        const float* __restrict__ Bgu,
        const float* __restrict__ Wd,  const float* __restrict__ Ad,
        const float* __restrict__ Bd,
        bf16_t* __restrict__ wgut, bf16_t* __restrict__ wdt,
        bf16_t* __restrict__ xb) {
    const int b = blockIdx.x, t = threadIdx.x;
    if (b < 1408) {
        prep_body<DMODEL, N2F>(Wgu, Agu, Bgu, wgut,
                               (b & 15) * 64, (b >> 4) * 64, t);
    } else if (b < 2112) {
        const int b2 = b - 1408;
        prep_body<DFF, DMODEL>(Wd, Ad, Bd, wdt,
                               (b2 % 44) * 64, (b2 / 44) * 64, t);
    } else {
        const int i = (b - 2112) * 256 + t;
        float4 v = ((const float4*)x)[i];
        bf16x4 o;
        o.x = (bf16_t)v.x; o.y = (bf16_t)v.y; o.z = (bf16_t)v.z; o.w = (bf16_t)v.w;
        ((bf16x4*)xb)[i] = o;
    }
}

// ---------------------------------------------------------------------------
// GEMM1: h[T][DFF] = silu(g)*u, [g|u] = X[T][1024] @ Wgu_t^T
// Block 256(M) x 128(F)-dual; 8 waves 2M x 4F; wave = 128 rows x 32 f x {g,u}.
// Buf (16384 bf16 = 32KB): A[256][32] @0, Bg[128][32] @8192, Bu @12288.
// 4 bufs = 128KB.
__global__ __launch_bounds__(512, 2) void gemm1(
        const bf16_t* __restrict__ X, const bf16_t* __restrict__ Wt,
        bf16_t* __restrict__ H) {
    __shared__ bf16_t lds[65536];
    const int t = threadIdx.x, l = t & 63;
    const int wid = t >> 6, wr = wid >> 2, wc = wid & 3;
    const int l15 = l & 15, lhi = l >> 4;
    const int wgl = ((int)blockIdx.x & 7) * 176 + ((int)blockIdx.x >> 3);
    const int tf = wgl % 22, tm = wgl / 22;
    const int mbase = tm * 256, fbase = tf * 128;
    const int srow = t >> 2;
    const int sc8 = ((t & 3) ^ (srow & 3)) * 8;
    const bf16_t* gA  = X + (size_t)(mbase + srow) * DMODEL + sc8;
    const bf16_t* gA2 = gA + (size_t)128 * DMODEL;
    const bf16_t* gBg = Wt + (size_t)(fbase + srow) * DMODEL + sc8;
    const bf16_t* gBu = Wt + (size_t)(DFF + fbase + srow) * DMODEL + sc8;
    const int rsw = (lhi ^ (l15 & 3)) * 8;
    const int aoff = (wr * 128 + l15) * 32 + rsw;
    const int boff = 8192 + (wc * 32 + l15) * 32 + rsw;

    f32x4 accg[8][2] = {}, accu[8][2] = {};
    bf16x8 a0[8], g0[2], u0[2], a1[8], g1[2], u1[2];
    const int NT1 = DMODEL / 32;  // 32

#define G1_STAGE(kt) do { const int kc = (kt) * 32;                               \
    bf16_t* p = lds + (((kt) & 3) << 14) + wid * 512;                             \
    gload16(gA  + kc, p);                                                         \
    gload16(gA2 + kc, p + 4096);                                                  \
    gload16(gBg + kc, p + 8192);                                                  \
    gload16(gBu + kc, p + 12288); } while (0)
#define G1_READ(aa, gg, uu, bi) do {                                              \
    const bf16_t* _pa = lds + ((bi) << 14) + aoff;                                \
    aa[0] = LD8(_pa);        aa[1] = LD8(_pa + 512);                              \
    aa[2] = LD8(_pa + 1024); aa[3] = LD8(_pa + 1536);                             \
    aa[4] = LD8(_pa + 2048); aa[5] = LD8(_pa + 2560);                             \
    aa[6] = LD8(_pa + 3072); aa[7] = LD8(_pa + 3584);                             \
    const bf16_t* _pb = lds + ((bi) << 14) + boff;                                \
    gg[0] = LD8(_pb);        gg[1] = LD8(_pb + 512);                              \
    uu[0] = LD8(_pb + 4096); uu[1] = LD8(_pb + 4608); } while (0)
#define G1_MFMA(aa, gg, uu) do {                                                  \
    _Pragma("unroll")                                                             \
    for (int m = 0; m < 8; ++m) {                                                 \
        MFMA(accg[m][0], aa[m], gg[0]); MFMA(accu[m][0], aa[m], uu[0]);           \
        MFMA(accg[m][1], aa[m], gg[1]); MFMA(accu[m][1], aa[m], uu[1]);           \
    } } while (0)
#define G1_ITER(kt, aaU, ggU, uuU, aaR, ggR, uuR) do {                            \
    VMW(4); BARM();                                                               \
    if ((kt) + 3 < NT1) G1_STAGE((kt) + 3);                                       \
    G1_READ(aaR, ggR, uuR, ((kt) + 1) & 3);                                       \
    G1_MFMA(aaU, ggU, uuU);                                                       \
    SGB_PATTERN(); } while (0)

    G1_STAGE(0); G1_STAGE(1); G1_STAGE(2);
    VMW(8); BARM();
    G1_READ(a0, g0, u0, 0);
    for (int kt2 = 0; kt2 < NT1 - 2; kt2 += 2) {
        G1_ITER(kt2,     a0, g0, u0, a1, g1, u1);
        G1_ITER(kt2 + 1, a1, g1, u1, a0, g0, u0);
    }
    VMW(0); BARM();
    G1_READ(a1, g1, u1, (NT1 - 1) & 3);
    G1_MFMA(a0, g0, u0);
    G1_MFMA(a1, g1, u1);
#undef G1_ITER
#undef G1_STAGE
#undef G1_READ
#undef G1_MFMA

    #pragma unroll
    for (int m = 0; m < 8; ++m)
        #pragma unroll
        for (int n = 0; n < 2; ++n)
            #pragma unroll
            for (int r = 0; r < 4; ++r) {
                int row = mbase + wr * 128 + m * 16 + lhi * 4 + r;
                int col = fbase + wc * 32 + n * 16 + l15;
                float g = accg[m][n][r], u = accu[m][n][r];
                H[(size_t)row * DFF + col] = (bf16_t)(g / (1.0f + __expf(-g)) * u);
            }
}

// ---------------------------------------------------------------------------
// GEMM2: out[T][1024] = H[T][2816] @ Wd_t^T   (fp32 out)
// Block 256(M) x 256(N); 8 waves 2M x 4N; wave 128x64. Same pipeline.
// Buf (16384 bf16): A[256][32] @0, B[256][32] @8192. 4 bufs = 128KB.
__global__ __launch_bounds__(512, 2) void gemm2(
        const bf16_t* __restrict__ Hm, const bf16_t* __restrict__ Wt,
        float* __restrict__ O) {
    __shared__ bf16_t lds[65536];
    const int t = threadIdx.x, l = t & 63;
    const int wid = t >> 6, wr = wid >> 2, wc = wid & 3;
    const int l15 = l & 15, lhi = l >> 4;
    const int wgl = ((int)blockIdx.x & 7) * 32 + ((int)blockIdx.x >> 3);
    const int tn = wgl % 4, tm = wgl / 4;
    const int mbase = tm * 256, nbase = tn * 256;
    const int srow = t >> 2;
    const int sc8 = ((t & 3) ^ (srow & 3)) * 8;
    const bf16_t* gA  = Hm + (size_t)(mbase + srow) * DFF + sc8;
    const bf16_t* gA2 = gA + (size_t)128 * DFF;
    const bf16_t* gB  = Wt + (size_t)(nbase + srow) * DFF + sc8;
    const bf16_t* gB2 = gB + (size_t)128 * DFF;
    const int rsw = (lhi ^ (l15 & 3)) * 8;
    const int aoff = (wr * 128 + l15) * 32 + rsw;
    const int boff = 8192 + (wc * 64 + l15) * 32 + rsw;

    f32x4 acc[8][4] = {};
    bf16x8 a0[8], b0[4], a1[8], b1[4];
    const int NT2 = DFF / 32;  // 88

#define G2_STAGE(kt) do { const int kc = (kt) * 32;                               \
    bf16_t* p = lds + (((kt) & 3) << 14) + wid * 512;                             \
    gload16(gA  + kc, p);                                                         \
    gload16(gA2 + kc, p + 4096);                                                  \
    gload16(gB  + kc, p + 8192);                                                  \
    gload16(gB2 + kc, p + 12288); } while (0)
#define G2_READ(aa, bb, bi) do {                                                  \
    const bf16_t* _pa = lds + ((bi) << 14) + aoff;                                \
    aa[0] = LD8(_pa);        aa[1] = LD8(_pa + 512);                              \
    aa[2] = LD8(_pa + 1024); aa[3] = LD8(_pa + 1536);                             \
    aa[4] = LD8(_pa + 2048); aa[5] = LD8(_pa + 2560);                             \
    aa[6] = LD8(_pa + 3072); aa[7] = LD8(_pa + 3584);                             \
    const bf16_t* _pb = lds + ((bi) << 14) + boff;                                \
    bb[0] = LD8(_pb);        bb[1] = LD8(_pb + 512);                              \
    bb[2] = LD8(_pb + 1024); bb[3] = LD8(_pb + 1536); } while (0)
#define G2_MFMA(aa, bb) do {                                                      \
    _Pragma("unroll")                                                             \
    for (int m = 0; m < 8; ++m) {                                                 \
        MFMA(acc[m][0], aa[m], bb[0]); MFMA(acc[m][1], aa[m], bb[1]);             \
        MFMA(acc[m][2], aa[m], bb[2]); MFMA(acc[m][3], aa[m], bb[3]);             \
    } } while (0)
#define G2_ITER(kt, aaU, bbU, aaR, bbR) do {                                      \
    VMW(4); BARM();                                                               \
    if ((kt) + 3 < NT2) G2_STAGE((kt) + 3);                                       \
    G2_READ(aaR, bbR, ((kt) + 1) & 3);                                            \
    G2_MFMA(aaU, bbU);                                                            \
    SGB_PATTERN(); } while (0)

    G2_STAGE(0); G2_STAGE(1); G2_STAGE(2);
    VMW(8); BARM();
    G2_READ(a0, b0, 0);
    for (int kt2 = 0; kt2 < NT2 - 2; kt2 += 2) {
        G2_ITER(kt2,     a0, b0, a1, b1);
        G2_ITER(kt2 + 1, a1, b1, a0, b0);
    }
    VMW(0); BARM();
    G2_READ(a1, b1, (NT2 - 1) & 3);
    G2_MFMA(a0, b0);
    G2_MFMA(a1, b1);
#undef G2_STAGE
#undef G2_READ
#undef G2_MFMA
#undef G2_ITER

    #pragma unroll
    for (int m = 0; m < 8; ++m)
        #pragma unroll
        for (int n = 0; n < 4; ++n)
            #pragma unroll
            for (int r = 0; r < 4; ++r) {
                int row = mbase + wr * 128 + m * 16 + lhi * 4 + r;
                int col = nbase + wc * 64 + n * 16 + l15;
                O[(size_t)row * DMODEL + col] = acc[m][n][r];
            }
}

// ---------------------------------------------------------------------------
extern "C" void kernel_launch(void* const* d_in, const int* in_sizes, int n_in,
                              void* d_out, int out_size, void* d_ws, size_t ws_size,
                              hipStream_t stream) {
    const float* x   = (const float*)d_in[0];
    const float* Wgu = (const float*)d_in[1];
    const float* Agu = (const float*)d_in[2];
    const float* Bgu = (const float*)d_in[3];
    const float* Wd  = (const float*)d_in[4];
    const float* Ad  = (const float*)d_in[5];
    const float* Bd  = (const float*)d_in[6];
    float* out = (float*)d_out;
    char* ws = (char*)d_ws;

    bf16_t* wgut = (bf16_t*)(ws);                    // [5632][1024]
    bf16_t* wdt  = (bf16_t*)(ws + 11534336);         // [1024][2816]
    bf16_t* xb   = (bf16_t*)(ws + 17301504);         // [16384][1024]
    bf16_t* hb   = (bf16_t*)(ws + 50855936);         // [16384][2816]

    prologue<<<18496, 256, 0, stream>>>(x, Wgu, Agu, Bgu, Wd, Ad, Bd,
                                        wgut, wdt, xb);
    gemm1<<<22 * 64, 512, 0, stream>>>(xb, wgut, hb);
    gemm2<<<8 * 32, 512, 0, stream>>>(hb, wdt, out);
}